// Round 4
// baseline (127.080 us; speedup 1.0000x reference)
//
#include <hip/hip_runtime.h>

// Per-sample 3x3 conv as bf16 implicit GEMM, NHWC, SAME padding.
// x: (32,128,128,32) f32; params: (32, 9216+32) f32; out: (32,128,128,32) f32
// Per sample: GEMM M=16384 px, N=32 f, K=288=(kh,kw,ci).
//
// R3 changes vs R2:
//  - Weights converted ONCE per sample by a prep kernel into d_ws as bf16
//    fragment layout ws[b][s*4+lg][f][8k] (16B units). Main kernel loads
//    B-fragments with coalesced per-lane dwordx4 (L2-resident), double-
//    buffered across the 9 taps. No weight LDS, no weight staging phase.
//  - LDS = x tile only (33.4 KB, cig*32B anti-conflict pad) -> 4 blocks/CU.
//  - Zero-fill merged into staging (pad cols/rows written as zeros): 1 barrier.
//  - Fallback (ws too small): LDS-weight variant (R2-style) via template.

typedef __attribute__((ext_vector_type(8))) short bf16x8;
typedef __attribute__((ext_vector_type(4))) float f32x4;

constexpr int HWD  = 128, CINC = 32, FC = 32;
constexpr int WSZ  = 9 * CINC * FC;         // 9216
constexpr int PSTR = WSZ + FC;              // 9248

// xs[cig=4][row=4][col=130][8ci as 16B], +32B pad per cig plane
constexpr int XS_PLANE  = 4 * 130 * 16;            // 8320
constexpr int XS_BYTES  = 4 * (XS_PLANE + 32);     // 33408
// fallback weight region (appended): wt[kgrp=36][f=32][8k as 16B]
constexpr int WT_BYTES  = 36 * 32 * 16;            // 18432

constexpr size_t WS_FRAGS = 32ull * 36 * 32;       // bf16x8 frags in workspace
constexpr size_t WS_NEED  = WS_FRAGS * 16;         // 589,824 B

__device__ __forceinline__ int xs_off(int cig, int r, int col) {
    return ((cig * 4 + r) * 130 + col) * 16 + cig * 32;
}
__device__ __forceinline__ int wt_off(int kgrp, int f) {
    return XS_BYTES + (kgrp * 32 + f) * 16;
}

__device__ __forceinline__ unsigned short f2bf(float f) {
    unsigned u = __float_as_uint(f);
    return (unsigned short)((u + 0x7FFFu + ((u >> 16) & 1u)) >> 16);  // RNE
}
__device__ __forceinline__ bf16x8 pack8(float4 a, float4 b) {
    bf16x8 r;
    r[0] = (short)f2bf(a.x); r[1] = (short)f2bf(a.y);
    r[2] = (short)f2bf(a.z); r[3] = (short)f2bf(a.w);
    r[4] = (short)f2bf(b.x); r[5] = (short)f2bf(b.y);
    r[6] = (short)f2bf(b.z); r[7] = (short)f2bf(b.w);
    return r;
}

// ---------------- prep: per-sample W fp32 -> bf16 fragment layout ----------
// ws[b*1152 + sg*32 + f] (bf16x8) = W[k = sg*8 .. sg*8+7][f],  sg = 0..35
__global__ __launch_bounds__(256) void wprep(
    const float* __restrict__ params, bf16x8* __restrict__ ws)
{
    const int b   = blockIdx.y;      // 0..31
    const int seg = blockIdx.x;      // 0..3 (288 items each)
    const float* __restrict__ pw = params + (size_t)b * PSTR;
    #pragma unroll
    for (int i = 0; i < 2; ++i) {
        const int idx = threadIdx.x + i * 256;
        if (idx < 288) {
            const int c  = seg * 288 + idx;     // 0..1151
            const int sg = c >> 5;
            const int f  = c & 31;
            const float* p = pw + (size_t)(sg * 8) * FC + f;
            float4 a, bb;
            a.x  = p[0 * FC]; a.y  = p[1 * FC]; a.z  = p[2 * FC]; a.w  = p[3 * FC];
            bb.x = p[4 * FC]; bb.y = p[5 * FC]; bb.z = p[6 * FC]; bb.w = p[7 * FC];
            ws[(size_t)b * 1152 + c] = pack8(a, bb);
        }
    }
}

// ---------------- main ----------------
template<bool USE_WS>
__global__ __launch_bounds__(256, USE_WS ? 4 : 3) void conv3x3_mfma(
    const float* __restrict__ x, const float* __restrict__ params,
    float* __restrict__ out, const bf16x8* __restrict__ ws)
{
    __shared__ __align__(16) unsigned char smem[XS_BYTES + (USE_WS ? 0 : WT_BYTES)];

    // XCD-bijective swizzle (2048 % 8 == 0): same-sample blocks share an XCD.
    const int hw      = blockIdx.x;
    const int logical = (hw & 7) * 256 + (hw >> 3);
    const int b       = logical >> 6;
    const int y0      = (logical & 63) * 2;

    const int t = threadIdx.x;
    const float* __restrict__ xb = x + (size_t)b * (HWD * HWD * CINC);
    const float* __restrict__ pw = params + (size_t)b * PSTR;

    // ---- stage x rows y0-1..y0+2 as bf16 (zeros for SAME-pad rows/cols)
    // item c = ((r*130 + col)*4 + cig), 2080 items; cig fastest => lanes 0..3
    // cover one col's full 128B (coalesced); cig*32 pad => conflict-free writes
    #pragma unroll
    for (int i = 0; i < 9; ++i) {
        const int c = t + i * 256;
        if (c < 2080) {
            const int cig      = c & 3;
            const unsigned q   = (unsigned)(c >> 2);     // 0..519
            const unsigned r   = q / 130u;
            const unsigned col = q - r * 130u;
            const int iy   = y0 - 1 + (int)r;
            const int icol = (int)col - 1;
            bf16x8 v = 0;
            if ((unsigned)iy < 128u && (unsigned)icol < 128u) {
                const float* p = xb + ((size_t)iy * HWD + icol) * CINC + cig * 8;
                v = pack8(*(const float4*)(p), *(const float4*)(p + 4));
            }
            *(bf16x8*)(smem + xs_off(cig, (int)r, (int)col)) = v;
        }
    }

    if constexpr (!USE_WS) {
        // fallback: stage W^T into LDS (R2 path)
        #pragma unroll
        for (int j = 0; j < 5; ++j) {
            const int c    = t + j * 256;
            const int kgrp = c >> 5;
            const int f    = c & 31;
            if (kgrp < 36) {
                const float* p = pw + (size_t)(kgrp * 8) * FC + f;
                float4 a, bb;
                a.x  = p[0 * FC]; a.y  = p[1 * FC]; a.z  = p[2 * FC]; a.w  = p[3 * FC];
                bb.x = p[4 * FC]; bb.y = p[5 * FC]; bb.z = p[6 * FC]; bb.w = p[7 * FC];
                *(bf16x8*)(smem + wt_off(kgrp, f)) = pack8(a, bb);
            }
        }
    }
    __syncthreads();

    // ---- main loop: wave -> 64 px (4 M-tiles) x 32 f (2 N-tiles)
    const int wv   = t >> 6;
    const int ln   = t & 63;
    const int lg   = ln >> 4;         // k-group
    const int li   = ln & 15;         // A row (pixel) / B col (f)
    const int yloc = wv >> 1;
    const int xw   = (wv & 1) * 64;

    f32x4 acc[4][2];
    #pragma unroll
    for (int i = 0; i < 4; ++i) { acc[i][0] = (f32x4)0.0f; acc[i][1] = (f32x4)0.0f; }

    const size_t wsb = (size_t)b * 1152 + lg * 32;   // bf16x8 units

    bf16x8 bc0, bc1;
    if constexpr (USE_WS) {
        bc0 = ws[wsb + li];
        bc1 = ws[wsb + 16 + li];
    }

    #pragma unroll
    for (int s = 0; s < 9; ++s) {
        const int kh = s / 3, kw = s % 3;
        bf16x8 b0, b1, bn0, bn1;
        if constexpr (USE_WS) {
            if (s < 8) {                      // double-buffer next tap
                bn0 = ws[wsb + (s + 1) * 128 + li];
                bn1 = ws[wsb + (s + 1) * 128 + 16 + li];
            }
            b0 = bc0; b1 = bc1;
        } else {
            b0 = *(const bf16x8*)(smem + wt_off(s * 4 + lg, li));
            b1 = *(const bf16x8*)(smem + wt_off(s * 4 + lg, 16 + li));
        }
        const int r = yloc + kh;
        const int colbase = xw + li + kw;
        #pragma unroll
        for (int tI = 0; tI < 4; ++tI) {
            const bf16x8 a = *(const bf16x8*)(smem + xs_off(lg, r, colbase + tI * 16));
            acc[tI][0] = __builtin_amdgcn_mfma_f32_16x16x32_bf16(a, b0, acc[tI][0], 0, 0, 0);
            acc[tI][1] = __builtin_amdgcn_mfma_f32_16x16x32_bf16(a, b1, acc[tI][1], 0, 0, 0);
        }
        if constexpr (USE_WS) { bc0 = bn0; bc1 = bn1; }
    }

    // ---- epilogue: C layout col=lane&15 (f), row=(lane>>4)*4+reg (pixel)
    const float bias0 = pw[WSZ + li];
    const float bias1 = pw[WSZ + 16 + li];
    const int yo = y0 + yloc;
    float* __restrict__ ob = out + ((size_t)(b * HWD + yo)) * (HWD * FC);

    #pragma unroll
    for (int tI = 0; tI < 4; ++tI) {
        #pragma unroll
        for (int reg = 0; reg < 4; ++reg) {
            const int px = xw + tI * 16 + lg * 4 + reg;
            float* q = ob + (size_t)px * FC;
            q[li]      = acc[tI][0][reg] + bias0;
            q[16 + li] = acc[tI][1][reg] + bias1;
        }
    }
}

extern "C" void kernel_launch(void* const* d_in, const int* in_sizes, int n_in,
                              void* d_out, int out_size, void* d_ws, size_t ws_size,
                              hipStream_t stream)
{
    const float* x      = (const float*)d_in[0];
    const float* params = (const float*)d_in[1];
    float*       out    = (float*)d_out;

    if (ws_size >= WS_NEED && d_ws != nullptr) {
        bf16x8* ws = (bf16x8*)d_ws;
        hipLaunchKernelGGL(wprep, dim3(4, 32), dim3(256), 0, stream, params, ws);
        hipLaunchKernelGGL((conv3x3_mfma<true>), dim3(2048), dim3(256), 0, stream,
                           x, params, out, (const bf16x8*)ws);
    } else {
        hipLaunchKernelGGL((conv3x3_mfma<false>), dim3(2048), dim3(256), 0, stream,
                           x, params, out, (const bf16x8*)nullptr);
    }
}